// Round 3
// baseline (377.455 us; speedup 1.0000x reference)
//
#include <hip/hip_runtime.h>
#include <math.h>

// LinOSSBlock: B=16, N=8192, M=128, dt=1
#define Bdim   16
#define Nseq   8192
#define Mdim   128
#define TS     64                    // timesteps per tile/chunk
#define CHUNKS (Nseq / TS)           // 128
#define CHAINS (Bdim * Mdim)         // 2048
#define NBLK   (Bdim * CHUNKS)       // 2048 blocks for kA/kC

typedef __bf16 bf16;
typedef __bf16 bf16x8 __attribute__((ext_vector_type(8)));
typedef __bf16 bf16x4 __attribute__((ext_vector_type(4)));
typedef float  f32x4  __attribute__((ext_vector_type(4)));

static __device__ __forceinline__ float gelu_exact(float x) {
    return 0.5f * x * (1.0f + erff(x * 0.70710678118654752f));
}

// stage a TS x 128 f32 tile -> bf16 LDS [TS][128]
static __device__ __forceinline__ void stage_u(const float* __restrict__ g,
                                               size_t rowBase, bf16* lds, int tid) {
    for (int i = tid; i < TS * 32; i += 256) {
        int r  = i >> 5;
        int c4 = i & 31;
        float4 v = ((const float4*)g)[(rowBase + (size_t)r) * 32 + c4];
        bf16x4 p;
        p[0] = (bf16)v.x; p[1] = (bf16)v.y; p[2] = (bf16)v.z; p[3] = (bf16)v.w;
        *reinterpret_cast<bf16x4*>(&lds[r * 128 + c4 * 4]) = p;
    }
}

// K=128 MFMA pass: acc[j] += lA(rows wave*16..+16) * W^T(cols j*16..+16)
// A/B frag (m89): lane holds row lane&15, k=(lane>>4)*8+j. C/D: col=lane&15, row=(lane>>4)*4+reg.
static __device__ __forceinline__ void mfma_pass(const bf16* lA, const bf16* __restrict__ gW,
                                                 f32x4 acc[8], int wave, int llo, int lhi) {
#pragma unroll
    for (int kk = 0; kk < 4; ++kk) {
        const int k0 = kk * 32 + lhi * 8;
        bf16x8 a = *reinterpret_cast<const bf16x8*>(&lA[(wave * 16 + llo) * 128 + k0]);
#pragma unroll
        for (int j = 0; j < 8; ++j) {
            bf16x8 b = *reinterpret_cast<const bf16x8*>(&gW[(j * 16 + llo) * 128 + k0]);
            acc[j] = __builtin_amdgcn_mfma_f32_16x16x32_bf16(a, b, acc[j], 0, 0, 0);
        }
    }
}

// ---------------------------------------------------------------------------
// kW: convert 5 weight matrices f32 -> bf16 (Bw, Cw, Dw, W1, W2), each 128x128
// grid = 5 blocks, one matrix per block (wave-uniform switch, no local array)
// ---------------------------------------------------------------------------
__global__ __launch_bounds__(256) void kw_conv(const float* __restrict__ Bw,
                                               const float* __restrict__ Cw,
                                               const float* __restrict__ Dw,
                                               const float* __restrict__ W1,
                                               const float* __restrict__ W2,
                                               bf16* __restrict__ wb) {
    const float* s;
    switch (blockIdx.x) {
        case 0:  s = Bw; break;
        case 1:  s = Cw; break;
        case 2:  s = Dw; break;
        case 3:  s = W1; break;
        default: s = W2; break;
    }
    bf16* d = wb + blockIdx.x * 16384;
    for (int i = threadIdx.x; i < 4096; i += 256) {
        float4 v = ((const float4*)s)[i];
        bf16x4 p;
        p[0] = (bf16)v.x; p[1] = (bf16)v.y; p[2] = (bf16)v.z; p[3] = (bf16)v.w;
        ((bf16x4*)d)[i] = p;
    }
}

// ---------------------------------------------------------------------------
// kA: fz = u@Bw^T + Bb (in LDS only) -> chunk-local scan from zero -> stateE
// ---------------------------------------------------------------------------
__global__ __launch_bounds__(256) void kA(const float* __restrict__ u,
                                          const float* __restrict__ Ad,
                                          const float* __restrict__ Bb,
                                          const bf16* __restrict__ Bwb,
                                          float2* __restrict__ stE) {
    __shared__ bf16 buf[TS * 128];   // u-tile, then fz-tile
    const int tid  = threadIdx.x;
    const int lane = tid & 63;
    const int wave = tid >> 6;
    const int llo  = lane & 15;
    const int lhi  = lane >> 4;
    const size_t rowBase = (size_t)blockIdx.x * TS;

    stage_u(u, rowBase, buf, tid);
    __syncthreads();

    f32x4 acc[8];
#pragma unroll
    for (int j = 0; j < 8; ++j) acc[j] = (f32x4){0.f, 0.f, 0.f, 0.f};
    mfma_pass(buf, Bwb, acc, wave, llo, lhi);

    __syncthreads();   // u-tile dead; overwrite with fz
#pragma unroll
    for (int j = 0; j < 8; ++j) {
        const int   col = j * 16 + llo;
        const float bb  = Bb[col];
#pragma unroll
        for (int r = 0; r < 4; ++r) {
            const int row = wave * 16 + lhi * 4 + r;
            buf[row * 128 + col] = (bf16)(acc[j][r] + bb);
        }
    }
    __syncthreads();

    if (tid < 128) {
        const int m  = tid;
        const float a  = fmaxf(Ad[m], 0.f);
        const float s  = 1.f / (1.f + a);
        const float sa = s * a;
        float z = 0.f, y = 0.f;
#pragma unroll 8
        for (int t = 0; t < TS; ++t) {
            float f  = (float)buf[t * 128 + m];
            float zp = z + f;
            float yn = s * (zp + y);
            z = s * zp - sa * y;
            y = yn;
        }
        const int b = blockIdx.x >> 7;     // / CHUNKS
        const int c = blockIdx.x & (CHUNKS - 1);
        stE[c * CHAINS + b * Mdim + m] = make_float2(z, y);
    }
}

// ---------------------------------------------------------------------------
// kB: sequential combine across 128 chunks per chain (S^TS via 6 squarings)
// ---------------------------------------------------------------------------
__global__ __launch_bounds__(256) void kB(const float2* __restrict__ stE,
                                          const float* __restrict__ Ad,
                                          float2* __restrict__ stS) {
    const int chain = blockIdx.x * 256 + threadIdx.x;
    const int m     = chain & 127;
    const float a   = fmaxf(Ad[m], 0.f);
    const float s   = 1.f / (1.f + a);
    float p00 = s, p01 = -s * a, p10 = s, p11 = s;
#pragma unroll
    for (int i = 0; i < 6; ++i) {      // S^64
        float q00 = p00 * p00 + p01 * p10;
        float q01 = p00 * p01 + p01 * p11;
        float q10 = p10 * p00 + p11 * p10;
        float q11 = p10 * p01 + p11 * p11;
        p00 = q00; p01 = q01; p10 = q10; p11 = q11;
    }
    float tz = 0.f, ty = 0.f;
    for (int c = 0; c < CHUNKS; ++c) {
        stS[c * CHAINS + chain] = make_float2(tz, ty);
        float2 e = stE[c * CHAINS + chain];
        float nz = p00 * tz + p01 * ty + e.x;
        float ny = p10 * tz + p11 * ty + e.y;
        tz = nz; ty = ny;
    }
}

// ---------------------------------------------------------------------------
// kC: recompute fz -> scan from stateS -> x@Cw^T + u@Dw^T -> GELU -> h
//     -> (h@W1^T+b1)*sigmoid(h@W2^T+b2) + u -> out
// ---------------------------------------------------------------------------
__global__ __launch_bounds__(256) void kC(const float* __restrict__ u,
                                          const float* __restrict__ Ad,
                                          const float* __restrict__ Bb,
                                          const float* __restrict__ Cb,
                                          const float* __restrict__ Db,
                                          const float* __restrict__ b1,
                                          const float* __restrict__ b2,
                                          const bf16* __restrict__ wb,
                                          const float2* __restrict__ stS,
                                          float* __restrict__ out) {
    __shared__ bf16 bufU[TS * 128];   // u-tile (bf16), lives whole kernel
    __shared__ bf16 bufX[TS * 128];   // fz -> x -> h
    const bf16* Bwb = wb;
    const bf16* Cwb = wb + 16384;
    const bf16* Dwb = wb + 32768;
    const bf16* W1b = wb + 49152;
    const bf16* W2b = wb + 65536;

    const int tid  = threadIdx.x;
    const int lane = tid & 63;
    const int wave = tid >> 6;
    const int llo  = lane & 15;
    const int lhi  = lane >> 4;
    const size_t rowBase = (size_t)blockIdx.x * TS;

    stage_u(u, rowBase, bufU, tid);
    __syncthreads();

    // fz = u @ Bw^T + Bb  -> bufX
    {
        f32x4 acc[8];
#pragma unroll
        for (int j = 0; j < 8; ++j) acc[j] = (f32x4){0.f, 0.f, 0.f, 0.f};
        mfma_pass(bufU, Bwb, acc, wave, llo, lhi);
#pragma unroll
        for (int j = 0; j < 8; ++j) {
            const int   col = j * 16 + llo;
            const float bb  = Bb[col];
#pragma unroll
            for (int r = 0; r < 4; ++r) {
                const int row = wave * 16 + lhi * 4 + r;
                bufX[row * 128 + col] = (bf16)(acc[j][r] + bb);
            }
        }
    }
    __syncthreads();

    // scan from global start state; overwrite bufX with x (= y sequence)
    if (tid < 128) {
        const int m  = tid;
        const float a  = fmaxf(Ad[m], 0.f);
        const float s  = 1.f / (1.f + a);
        const float sa = s * a;
        const int b = blockIdx.x >> 7;
        const int c = blockIdx.x & (CHUNKS - 1);
        float2 st = stS[c * CHAINS + b * Mdim + m];
        float z = st.x, y = st.y;
#pragma unroll 8
        for (int t = 0; t < TS; ++t) {
            float f  = (float)bufX[t * 128 + m];
            float zp = z + f;
            float yn = s * (zp + y);
            z = s * zp - sa * y;
            y = yn;
            bufX[t * 128 + m] = (bf16)y;
        }
    }
    __syncthreads();

    // h = gelu(x@Cw^T + u@Dw^T + Cb + Db)
    {
        f32x4 acc[8];
#pragma unroll
        for (int j = 0; j < 8; ++j) acc[j] = (f32x4){0.f, 0.f, 0.f, 0.f};
        mfma_pass(bufX, Cwb, acc, wave, llo, lhi);
        mfma_pass(bufU, Dwb, acc, wave, llo, lhi);
        __syncthreads();   // all reads of bufX done before overwriting with h
#pragma unroll
        for (int j = 0; j < 8; ++j) {
            const int   col = j * 16 + llo;
            const float bb  = Cb[col] + Db[col];
#pragma unroll
            for (int r = 0; r < 4; ++r) {
                const int row = wave * 16 + lhi * 4 + r;
                float v = acc[j][r] + bb;
                bufX[row * 128 + col] = (bf16)gelu_exact(v);
            }
        }
    }
    __syncthreads();

    // out = (h@W1^T + b1) * sigmoid(h@W2^T + b2) + u
    {
        f32x4 acc1[8], acc2[8];
#pragma unroll
        for (int j = 0; j < 8; ++j) {
            acc1[j] = (f32x4){0.f, 0.f, 0.f, 0.f};
            acc2[j] = (f32x4){0.f, 0.f, 0.f, 0.f};
        }
#pragma unroll
        for (int kk = 0; kk < 4; ++kk) {
            const int k0 = kk * 32 + lhi * 8;
            bf16x8 a = *reinterpret_cast<const bf16x8*>(&bufX[(wave * 16 + llo) * 128 + k0]);
#pragma unroll
            for (int j = 0; j < 8; ++j) {
                bf16x8 w1 = *reinterpret_cast<const bf16x8*>(&W1b[(j * 16 + llo) * 128 + k0]);
                bf16x8 w2 = *reinterpret_cast<const bf16x8*>(&W2b[(j * 16 + llo) * 128 + k0]);
                acc1[j] = __builtin_amdgcn_mfma_f32_16x16x32_bf16(a, w1, acc1[j], 0, 0, 0);
                acc2[j] = __builtin_amdgcn_mfma_f32_16x16x32_bf16(a, w2, acc2[j], 0, 0, 0);
            }
        }
#pragma unroll
        for (int j = 0; j < 8; ++j) {
            const int   col = j * 16 + llo;
            const float bb1 = b1[col];
            const float bb2 = b2[col];
#pragma unroll
            for (int r = 0; r < 4; ++r) {
                const int row = wave * 16 + lhi * 4 + r;
                const size_t idx = (rowBase + row) * 128 + col;
                float t1 = acc1[j][r] + bb1;
                float t2 = acc2[j][r] + bb2;
                float g  = t1 * (1.f / (1.f + expf(-t2)));
                out[idx] = g + u[idx];
            }
        }
    }
}

// ---------------------------------------------------------------------------
// launch
// ---------------------------------------------------------------------------
extern "C" void kernel_launch(void* const* d_in, const int* in_sizes, int n_in,
                              void* d_out, int out_size, void* d_ws, size_t ws_size,
                              hipStream_t stream) {
    const float* u  = (const float*)d_in[0];
    const float* Ad = (const float*)d_in[1];
    const float* Bw = (const float*)d_in[2];
    const float* Bb = (const float*)d_in[3];
    const float* Cw = (const float*)d_in[4];
    const float* Cb = (const float*)d_in[5];
    const float* Dw = (const float*)d_in[6];
    const float* Db = (const float*)d_in[7];
    const float* W1 = (const float*)d_in[8];
    const float* b1 = (const float*)d_in[9];
    const float* W2 = (const float*)d_in[10];
    const float* b2 = (const float*)d_in[11];
    float* out = (float*)d_out;

    char* ws = (char*)d_ws;
    bf16*   wb  = (bf16*)ws;                                   // 5*32 KB = 160 KB
    float2* stE = (float2*)(ws + 256 * 1024);                  // 2 MB
    float2* stS = (float2*)(ws + 256 * 1024 + (size_t)CHUNKS * CHAINS * 8);

    kw_conv<<<5, 256, 0, stream>>>(Bw, Cw, Dw, W1, W2, wb);
    kA<<<NBLK, 256, 0, stream>>>(u, Ad, Bb, wb, stE);
    kB<<<CHAINS / 256, 256, 0, stream>>>(stE, Ad, stS);
    kC<<<NBLK, 256, 0, stream>>>(u, Ad, Bb, Cb, Db, b1, b2, wb, stS, out);
}

// Round 4
// 222.811 us; speedup vs baseline: 1.6941x; 1.6941x over previous
//
#include <hip/hip_runtime.h>
#include <math.h>

// LinOSSBlock: B=16, N=8192, M=128, dt=1
#define Bdim   16
#define Nseq   8192
#define Mdim   128
#define TS     64                    // timesteps per tile/chunk
#define CHUNKS (Nseq / TS)           // 128
#define CHAINS (Bdim * Mdim)         // 2048
#define NBLK   (Bdim * CHUNKS)       // 2048 blocks for kA/kC

typedef __bf16 bf16;
typedef __bf16 bf16x8 __attribute__((ext_vector_type(8)));
typedef __bf16 bf16x4 __attribute__((ext_vector_type(4)));
typedef float  f32x4  __attribute__((ext_vector_type(4)));

static __device__ __forceinline__ float gelu_exact(float x) {
    return 0.5f * x * (1.0f + erff(x * 0.70710678118654752f));
}

// stage a TS x 128 f32 tile -> bf16 LDS [TS][128]
static __device__ __forceinline__ void stage_u(const float* __restrict__ g,
                                               size_t rowBase, bf16* lds, int tid) {
    for (int i = tid; i < TS * 32; i += 256) {
        int r  = i >> 5;
        int c4 = i & 31;
        float4 v = ((const float4*)g)[(rowBase + (size_t)r) * 32 + c4];
        bf16x4 p;
        p[0] = (bf16)v.x; p[1] = (bf16)v.y; p[2] = (bf16)v.z; p[3] = (bf16)v.w;
        *reinterpret_cast<bf16x4*>(&lds[r * 128 + c4 * 4]) = p;
    }
}

// Column-strip GEMM pass: this wave covers output cols [j0*16, j0*16+32), all TS rows.
// Weight fragments (8 x bf16x8 = 32 VGPRs) hoisted ONCE per pass -> loads pipelined,
// reused across all 4 row-tiles (vs 32 dependent per-MFMA loads before).
// A/B frag (m89): lane holds row lane&15, k=(lane>>4)*8+j. C/D: col=lane&15, row=(lane>>4)*4+reg.
static __device__ __forceinline__ void pass_colstrip(const bf16* lA, const bf16* __restrict__ gW,
                                                     f32x4 acc[4][2], int j0, int llo, int lhi) {
    bf16x8 bfr[2][4];
#pragma unroll
    for (int jj = 0; jj < 2; ++jj)
#pragma unroll
        for (int kk = 0; kk < 4; ++kk)
            bfr[jj][kk] = *reinterpret_cast<const bf16x8*>(
                &gW[((j0 + jj) * 16 + llo) * 128 + kk * 32 + lhi * 8]);
#pragma unroll
    for (int kk = 0; kk < 4; ++kk) {
        const int k0 = kk * 32 + lhi * 8;
#pragma unroll
        for (int rt = 0; rt < 4; ++rt) {
            bf16x8 a = *reinterpret_cast<const bf16x8*>(&lA[(rt * 16 + llo) * 128 + k0]);
#pragma unroll
            for (int jj = 0; jj < 2; ++jj)
                acc[rt][jj] = __builtin_amdgcn_mfma_f32_16x16x32_bf16(a, bfr[jj][kk], acc[rt][jj], 0, 0, 0);
        }
    }
}

// ---------------------------------------------------------------------------
// kW: convert 5 weight matrices f32 -> bf16 (Bw, Cw, Dw, W1, W2), each 128x128
// ---------------------------------------------------------------------------
__global__ __launch_bounds__(256) void kw_conv(const float* __restrict__ Bw,
                                               const float* __restrict__ Cw,
                                               const float* __restrict__ Dw,
                                               const float* __restrict__ W1,
                                               const float* __restrict__ W2,
                                               bf16* __restrict__ wb) {
    const float* s;
    switch (blockIdx.x) {
        case 0:  s = Bw; break;
        case 1:  s = Cw; break;
        case 2:  s = Dw; break;
        case 3:  s = W1; break;
        default: s = W2; break;
    }
    bf16* d = wb + blockIdx.x * 16384;
    for (int i = threadIdx.x; i < 4096; i += 256) {
        float4 v = ((const float4*)s)[i];
        bf16x4 p;
        p[0] = (bf16)v.x; p[1] = (bf16)v.y; p[2] = (bf16)v.z; p[3] = (bf16)v.w;
        ((bf16x4*)d)[i] = p;
    }
}

// ---------------------------------------------------------------------------
// kA: fz = u@Bw^T + Bb (in LDS only) -> chunk-local scan from zero -> stateE
// ---------------------------------------------------------------------------
__global__ __launch_bounds__(256, 4) void kA(const float* __restrict__ u,
                                             const float* __restrict__ Ad,
                                             const float* __restrict__ Bb,
                                             const bf16* __restrict__ Bwb,
                                             float2* __restrict__ stE) {
    __shared__ bf16 buf[TS * 128];   // u-tile, then fz-tile
    const int tid  = threadIdx.x;
    const int lane = tid & 63;
    const int wave = tid >> 6;
    const int llo  = lane & 15;
    const int lhi  = lane >> 4;
    const int j0   = wave * 2;
    const size_t rowBase = (size_t)blockIdx.x * TS;

    // hoisted independent loads (off critical path)
    const int   m   = tid & 127;
    const float a_  = fmaxf(Ad[m], 0.f);
    const float s_  = 1.f / (1.f + a_);
    const float sa_ = s_ * a_;
    float bb[2];
#pragma unroll
    for (int jj = 0; jj < 2; ++jj) bb[jj] = Bb[(j0 + jj) * 16 + llo];

    stage_u(u, rowBase, buf, tid);
    __syncthreads();

    f32x4 acc[4][2];
#pragma unroll
    for (int rt = 0; rt < 4; ++rt)
#pragma unroll
        for (int jj = 0; jj < 2; ++jj) acc[rt][jj] = (f32x4){0.f, 0.f, 0.f, 0.f};
    pass_colstrip(buf, Bwb, acc, j0, llo, lhi);

    __syncthreads();   // all A-reads of buf done; overwrite with fz
#pragma unroll
    for (int jj = 0; jj < 2; ++jj) {
        const int col = (j0 + jj) * 16 + llo;
#pragma unroll
        for (int rt = 0; rt < 4; ++rt)
#pragma unroll
            for (int r = 0; r < 4; ++r)
                buf[(rt * 16 + lhi * 4 + r) * 128 + col] = (bf16)(acc[rt][jj][r] + bb[jj]);
    }
    __syncthreads();

    if (tid < 128) {
        float z = 0.f, y = 0.f;
#pragma unroll 8
        for (int t = 0; t < TS; ++t) {
            float f  = (float)buf[t * 128 + m];
            float zp = z + f;
            float yn = s_ * (zp + y);
            z = s_ * zp - sa_ * y;
            y = yn;
        }
        const int b = blockIdx.x >> 7;     // / CHUNKS
        const int c = blockIdx.x & (CHUNKS - 1);
        stE[c * CHAINS + b * Mdim + m] = make_float2(z, y);
    }
}

// ---------------------------------------------------------------------------
// kB: sequential combine across 128 chunks per chain (S^TS via 6 squarings)
// 64-thread blocks -> 32 blocks for a little more spread
// ---------------------------------------------------------------------------
__global__ __launch_bounds__(64) void kB(const float2* __restrict__ stE,
                                         const float* __restrict__ Ad,
                                         float2* __restrict__ stS) {
    const int chain = blockIdx.x * 64 + threadIdx.x;
    const int m     = chain & 127;
    const float a   = fmaxf(Ad[m], 0.f);
    const float s   = 1.f / (1.f + a);
    float p00 = s, p01 = -s * a, p10 = s, p11 = s;
#pragma unroll
    for (int i = 0; i < 6; ++i) {      // S^64
        float q00 = p00 * p00 + p01 * p10;
        float q01 = p00 * p01 + p01 * p11;
        float q10 = p10 * p00 + p11 * p10;
        float q11 = p10 * p01 + p11 * p11;
        p00 = q00; p01 = q01; p10 = q10; p11 = q11;
    }
    float tz = 0.f, ty = 0.f;
    for (int c = 0; c < CHUNKS; ++c) {
        stS[c * CHAINS + chain] = make_float2(tz, ty);
        float2 e = stE[c * CHAINS + chain];
        float nz = p00 * tz + p01 * ty + e.x;
        float ny = p10 * tz + p11 * ty + e.y;
        tz = nz; ty = ny;
    }
}

// ---------------------------------------------------------------------------
// kC: recompute fz -> scan from stateS -> x@Cw^T + u@Dw^T -> GELU -> h
//     -> (h@W1^T+b1)*sigmoid(h@W2^T+b2) + u -> out
// ---------------------------------------------------------------------------
__global__ __launch_bounds__(256, 3) void kC(const float* __restrict__ u,
                                             const float* __restrict__ Ad,
                                             const float* __restrict__ Bb,
                                             const float* __restrict__ Cb,
                                             const float* __restrict__ Db,
                                             const float* __restrict__ b1,
                                             const float* __restrict__ b2,
                                             const bf16* __restrict__ wb,
                                             const float2* __restrict__ stS,
                                             float* __restrict__ out) {
    __shared__ bf16 bufU[TS * 128];   // u-tile (bf16), lives whole kernel
    __shared__ bf16 bufX[TS * 128];   // fz -> x -> h
    const bf16* Bwb = wb;
    const bf16* Cwb = wb + 16384;
    const bf16* Dwb = wb + 32768;
    const bf16* W1b = wb + 49152;
    const bf16* W2b = wb + 65536;

    const int tid  = threadIdx.x;
    const int lane = tid & 63;
    const int wave = tid >> 6;
    const int llo  = lane & 15;
    const int lhi  = lane >> 4;
    const int j0   = wave * 2;
    const size_t rowBase = (size_t)blockIdx.x * TS;

    // hoisted independent loads: scan state + constants + all biases
    const int   m   = tid & 127;
    const float a_  = fmaxf(Ad[m], 0.f);
    const float s_  = 1.f / (1.f + a_);
    const float sa_ = s_ * a_;
    const int   b   = blockIdx.x >> 7;
    const int   c   = blockIdx.x & (CHUNKS - 1);
    const float2 st = stS[c * CHAINS + b * Mdim + m];   // valid addr for all tids
    float bbB[2], bbCD[2], bb1[2], bb2[2];
#pragma unroll
    for (int jj = 0; jj < 2; ++jj) {
        const int col = (j0 + jj) * 16 + llo;
        bbB[jj]  = Bb[col];
        bbCD[jj] = Cb[col] + Db[col];
        bb1[jj]  = b1[col];
        bb2[jj]  = b2[col];
    }

    stage_u(u, rowBase, bufU, tid);
    __syncthreads();

    f32x4 acc[4][2];
#pragma unroll
    for (int rt = 0; rt < 4; ++rt)
#pragma unroll
        for (int jj = 0; jj < 2; ++jj) acc[rt][jj] = (f32x4){0.f, 0.f, 0.f, 0.f};

    // fz = u @ Bw^T + Bb  -> bufX (reads bufU, writes bufX: no barrier needed between)
    pass_colstrip(bufU, Bwb, acc, j0, llo, lhi);
#pragma unroll
    for (int jj = 0; jj < 2; ++jj) {
        const int col = (j0 + jj) * 16 + llo;
#pragma unroll
        for (int rt = 0; rt < 4; ++rt)
#pragma unroll
            for (int r = 0; r < 4; ++r)
                bufX[(rt * 16 + lhi * 4 + r) * 128 + col] = (bf16)(acc[rt][jj][r] + bbB[jj]);
    }
    __syncthreads();

    // scan from global start state; overwrite bufX with x (= y sequence)
    if (tid < 128) {
        float z = st.x, y = st.y;
#pragma unroll 8
        for (int t = 0; t < TS; ++t) {
            float f  = (float)bufX[t * 128 + m];
            float zp = z + f;
            float yn = s_ * (zp + y);
            z = s_ * zp - sa_ * y;
            y = yn;
            bufX[t * 128 + m] = (bf16)y;
        }
    }
    __syncthreads();

    // h = gelu(x@Cw^T + u@Dw^T + Cb + Db)
#pragma unroll
    for (int rt = 0; rt < 4; ++rt)
#pragma unroll
        for (int jj = 0; jj < 2; ++jj) acc[rt][jj] = (f32x4){0.f, 0.f, 0.f, 0.f};
    pass_colstrip(bufX, Cwb, acc, j0, llo, lhi);
    pass_colstrip(bufU, Dwb, acc, j0, llo, lhi);
    __syncthreads();   // other waves' reads of bufX done before overwrite with h
#pragma unroll
    for (int jj = 0; jj < 2; ++jj) {
        const int col = (j0 + jj) * 16 + llo;
#pragma unroll
        for (int rt = 0; rt < 4; ++rt)
#pragma unroll
            for (int r = 0; r < 4; ++r)
                bufX[(rt * 16 + lhi * 4 + r) * 128 + col] =
                    (bf16)gelu_exact(acc[rt][jj][r] + bbCD[jj]);
    }
    __syncthreads();

    // t2 = h@W2^T + b2 -> sigmoid kept in registers (lane mapping identical to W1 pass)
#pragma unroll
    for (int rt = 0; rt < 4; ++rt)
#pragma unroll
        for (int jj = 0; jj < 2; ++jj) acc[rt][jj] = (f32x4){0.f, 0.f, 0.f, 0.f};
    pass_colstrip(bufX, W2b, acc, j0, llo, lhi);
    f32x4 sig[4][2];
#pragma unroll
    for (int rt = 0; rt < 4; ++rt)
#pragma unroll
        for (int jj = 0; jj < 2; ++jj)
#pragma unroll
            for (int r = 0; r < 4; ++r)
                sig[rt][jj][r] = 1.f / (1.f + expf(-(acc[rt][jj][r] + bb2[jj])));

    // t1 = h@W1^T + b1 (bufX unchanged since last barrier -> no sync needed)
#pragma unroll
    for (int rt = 0; rt < 4; ++rt)
#pragma unroll
        for (int jj = 0; jj < 2; ++jj) acc[rt][jj] = (f32x4){0.f, 0.f, 0.f, 0.f};
    pass_colstrip(bufX, W1b, acc, j0, llo, lhi);

#pragma unroll
    for (int jj = 0; jj < 2; ++jj) {
        const int col = (j0 + jj) * 16 + llo;
#pragma unroll
        for (int rt = 0; rt < 4; ++rt)
#pragma unroll
            for (int r = 0; r < 4; ++r) {
                const int row = rt * 16 + lhi * 4 + r;
                const size_t idx = (rowBase + row) * 128 + col;
                float g = (acc[rt][jj][r] + bb1[jj]) * sig[rt][jj][r];
                out[idx] = g + u[idx];
            }
    }
}

// ---------------------------------------------------------------------------
// launch
// ---------------------------------------------------------------------------
extern "C" void kernel_launch(void* const* d_in, const int* in_sizes, int n_in,
                              void* d_out, int out_size, void* d_ws, size_t ws_size,
                              hipStream_t stream) {
    const float* u  = (const float*)d_in[0];
    const float* Ad = (const float*)d_in[1];
    const float* Bw = (const float*)d_in[2];
    const float* Bb = (const float*)d_in[3];
    const float* Cw = (const float*)d_in[4];
    const float* Cb = (const float*)d_in[5];
    const float* Dw = (const float*)d_in[6];
    const float* Db = (const float*)d_in[7];
    const float* W1 = (const float*)d_in[8];
    const float* b1 = (const float*)d_in[9];
    const float* W2 = (const float*)d_in[10];
    const float* b2 = (const float*)d_in[11];
    float* out = (float*)d_out;

    char* ws = (char*)d_ws;
    bf16*   wb  = (bf16*)ws;                                   // 5*32 KB = 160 KB
    float2* stE = (float2*)(ws + 256 * 1024);                  // 2 MB
    float2* stS = (float2*)(ws + 256 * 1024 + (size_t)CHUNKS * CHAINS * 8);

    kw_conv<<<5, 256, 0, stream>>>(Bw, Cw, Dw, W1, W2, wb);
    kA<<<NBLK, 256, 0, stream>>>(u, Ad, Bb, wb, stE);
    kB<<<CHAINS / 64, 64, 0, stream>>>(stE, Ad, stS);
    kC<<<NBLK, 256, 0, stream>>>(u, Ad, Bb, Cb, Db, b1, b2, wb, stS, out);
}

// Round 5
// 215.141 us; speedup vs baseline: 1.7545x; 1.0357x over previous
//
#include <hip/hip_runtime.h>
#include <math.h>

// LinOSSBlock: B=16, N=8192, M=128, dt=1
#define Bdim   16
#define Nseq   8192
#define Mdim   128
#define TS     64                    // timesteps per tile/chunk
#define CHUNKS (Nseq / TS)           // 128
#define CHAINS (Bdim * Mdim)         // 2048
#define NBLK   (Bdim * CHUNKS)       // 2048 blocks for kA/kC
#define LDSP   136                   // padded LDS row pitch (bf16): 272 B = 16B-aligned,
                                     // row stride ≡ 4 dwords mod 32 banks -> kills 16-way conflicts

typedef __bf16 bf16;
typedef __bf16 bf16x8 __attribute__((ext_vector_type(8)));
typedef __bf16 bf16x4 __attribute__((ext_vector_type(4)));
typedef float  f32x4  __attribute__((ext_vector_type(4)));

// exact-grade GELU via Abramowitz-Stegun 7.1.26 erfc (|eps| < 1.5e-7), ~15 VALU vs ~50 for erff
static __device__ __forceinline__ float gelu_fast(float x) {
    float ax = 0.70710678118654752f * fabsf(x);
    float t  = __builtin_amdgcn_rcpf(fmaf(0.3275911f, ax, 1.0f));
    float p  = t * fmaf(t, fmaf(t, fmaf(t, fmaf(t, 1.061405429f, -1.453152027f),
                                        1.421413741f), -0.284496736f), 0.254829592f);
    float erfc_v = p * __expf(-ax * ax);      // = 1 - erf(ax), ax >= 0
    float half_t = 0.5f * x * erfc_v;
    return (x >= 0.f) ? x - half_t : half_t;  // 0.5*x*(1+erf(x/sqrt2))
}

static __device__ __forceinline__ float sigmoid_fast(float x) {
    return __builtin_amdgcn_rcpf(1.f + __expf(-x));
}

// stage a TS x 128 f32 tile -> bf16 LDS [TS][LDSP]
static __device__ __forceinline__ void stage_u(const float* __restrict__ g,
                                               size_t rowBase, bf16* lds, int tid) {
    for (int i = tid; i < TS * 32; i += 256) {
        int r  = i >> 5;
        int c4 = i & 31;
        float4 v = ((const float4*)g)[(rowBase + (size_t)r) * 32 + c4];
        bf16x4 p;
        p[0] = (bf16)v.x; p[1] = (bf16)v.y; p[2] = (bf16)v.z; p[3] = (bf16)v.w;
        *reinterpret_cast<bf16x4*>(&lds[r * LDSP + c4 * 4]) = p;
    }
}

// Column-strip GEMM pass: wave covers output cols [j0*16, j0*16+32), all TS rows.
// Weight fragments hoisted once per pass (8 x bf16x8), reused across 4 row-tiles.
// A/B frag (m89): lane holds row lane&15, k=(lane>>4)*8+j. C/D: col=lane&15, row=(lane>>4)*4+reg.
static __device__ __forceinline__ void pass_colstrip(const bf16* lA, const bf16* __restrict__ gW,
                                                     f32x4 acc[4][2], int j0, int llo, int lhi) {
    bf16x8 bfr[2][4];
#pragma unroll
    for (int jj = 0; jj < 2; ++jj)
#pragma unroll
        for (int kk = 0; kk < 4; ++kk)
            bfr[jj][kk] = *reinterpret_cast<const bf16x8*>(
                &gW[((j0 + jj) * 16 + llo) * 128 + kk * 32 + lhi * 8]);
#pragma unroll
    for (int kk = 0; kk < 4; ++kk) {
        const int k0 = kk * 32 + lhi * 8;
#pragma unroll
        for (int rt = 0; rt < 4; ++rt) {
            bf16x8 a = *reinterpret_cast<const bf16x8*>(&lA[(rt * 16 + llo) * LDSP + k0]);
#pragma unroll
            for (int jj = 0; jj < 2; ++jj)
                acc[rt][jj] = __builtin_amdgcn_mfma_f32_16x16x32_bf16(a, bfr[jj][kk], acc[rt][jj], 0, 0, 0);
        }
    }
}

// ---------------------------------------------------------------------------
// kW: convert 5 weight matrices f32 -> bf16 (Bw, Cw, Dw, W1, W2), each 128x128
// ---------------------------------------------------------------------------
__global__ __launch_bounds__(256) void kw_conv(const float* __restrict__ Bw,
                                               const float* __restrict__ Cw,
                                               const float* __restrict__ Dw,
                                               const float* __restrict__ W1,
                                               const float* __restrict__ W2,
                                               bf16* __restrict__ wb) {
    const float* s;
    switch (blockIdx.x) {
        case 0:  s = Bw; break;
        case 1:  s = Cw; break;
        case 2:  s = Dw; break;
        case 3:  s = W1; break;
        default: s = W2; break;
    }
    bf16* d = wb + blockIdx.x * 16384;
    for (int i = threadIdx.x; i < 4096; i += 256) {
        float4 v = ((const float4*)s)[i];
        bf16x4 p;
        p[0] = (bf16)v.x; p[1] = (bf16)v.y; p[2] = (bf16)v.z; p[3] = (bf16)v.w;
        ((bf16x4*)d)[i] = p;
    }
}

// ---------------------------------------------------------------------------
// kA: fz = u@Bw^T + Bb (in LDS only) -> chunk-local scan from zero -> stE[chain][chunk]
// ---------------------------------------------------------------------------
__global__ __launch_bounds__(256, 4) void kA(const float* __restrict__ u,
                                             const float* __restrict__ Ad,
                                             const float* __restrict__ Bb,
                                             const bf16* __restrict__ Bwb,
                                             float2* __restrict__ stE) {
    __shared__ bf16 buf[TS * LDSP];   // u-tile, then fz-tile
    const int tid  = threadIdx.x;
    const int lane = tid & 63;
    const int wave = tid >> 6;
    const int llo  = lane & 15;
    const int lhi  = lane >> 4;
    const int j0   = wave * 2;
    const size_t rowBase = (size_t)blockIdx.x * TS;

    const int   m   = tid & 127;
    const float a_  = fmaxf(Ad[m], 0.f);
    const float s_  = 1.f / (1.f + a_);
    const float sa_ = s_ * a_;
    float bb[2];
#pragma unroll
    for (int jj = 0; jj < 2; ++jj) bb[jj] = Bb[(j0 + jj) * 16 + llo];

    stage_u(u, rowBase, buf, tid);
    __syncthreads();

    f32x4 acc[4][2];
#pragma unroll
    for (int rt = 0; rt < 4; ++rt)
#pragma unroll
        for (int jj = 0; jj < 2; ++jj) acc[rt][jj] = (f32x4){0.f, 0.f, 0.f, 0.f};
    pass_colstrip(buf, Bwb, acc, j0, llo, lhi);

    __syncthreads();   // all A-reads done; overwrite buf with fz
#pragma unroll
    for (int jj = 0; jj < 2; ++jj) {
        const int col = (j0 + jj) * 16 + llo;
#pragma unroll
        for (int rt = 0; rt < 4; ++rt)
#pragma unroll
            for (int r = 0; r < 4; ++r)
                buf[(rt * 16 + lhi * 4 + r) * LDSP + col] = (bf16)(acc[rt][jj][r] + bb[jj]);
    }
    __syncthreads();

    if (tid < 128) {
        float z = 0.f, y = 0.f;
#pragma unroll 8
        for (int t = 0; t < TS; ++t) {
            float f  = (float)buf[t * LDSP + m];
            float zp = z + f;
            float yn = s_ * (zp + y);
            z = s_ * zp - sa_ * y;
            y = yn;
        }
        const int b = blockIdx.x >> 7;     // / CHUNKS
        const int c = blockIdx.x & (CHUNKS - 1);
        stE[(size_t)(b * Mdim + m) * CHUNKS + c] = make_float2(z, y);   // [chain][chunk]
    }
}

// ---------------------------------------------------------------------------
// kB: wave-per-chain Kogge-Stone scan over 128 chunk maps.
// Per chain the chunk map is (S^64, e_c) with uniform S -> composition is
// v' = Q_j * v_prev + v, Q_j = S^(128*2^j). 2 chunks/lane + 6 shuffle steps.
// ---------------------------------------------------------------------------
__global__ __launch_bounds__(256) void kB(const float2* __restrict__ stE,
                                          const float* __restrict__ Ad,
                                          float2* __restrict__ stS) {
    const int lane  = threadIdx.x & 63;
    const int wave  = threadIdx.x >> 6;
    const int chain = blockIdx.x * 4 + wave;
    const int m     = chain & 127;
    const float a   = fmaxf(Ad[m], 0.f);
    const float s   = 1.f / (1.f + a);
    // S^64 by 6 squarings
    float p00 = s, p01 = -s * a, p10 = s, p11 = s;
#pragma unroll
    for (int i = 0; i < 6; ++i) {
        float q00 = p00 * p00 + p01 * p10;
        float q01 = p00 * p01 + p01 * p11;
        float q10 = p10 * p00 + p11 * p10;
        float q11 = p10 * p01 + p11 * p11;
        p00 = q00; p01 = q01; p10 = q10; p11 = q11;
    }
    // load this lane's 2 chunk end-states (coalesced: [chain][chunk])
    const float2 e0 = stE[(size_t)chain * CHUNKS + lane * 2];
    const float2 e1 = stE[(size_t)chain * CHUNKS + lane * 2 + 1];
    // intra-lane combine: prefix at end of chunk 2*lane+1
    float vx = p00 * e0.x + p01 * e0.y + e1.x;
    float vy = p10 * e0.x + p11 * e0.y + e1.y;
    // Q_0 = S^128
    float q00 = p00 * p00 + p01 * p10;
    float q01 = p00 * p01 + p01 * p11;
    float q10 = p10 * p00 + p11 * p10;
    float q11 = p10 * p01 + p11 * p11;
#pragma unroll
    for (int j = 0; j < 6; ++j) {
        const int d = 1 << j;
        float ox = __shfl_up(vx, d);
        float oy = __shfl_up(vy, d);
        if (lane >= d) {
            vx = q00 * ox + q01 * oy + vx;
            vy = q10 * ox + q11 * oy + vy;
        }
        float n00 = q00 * q00 + q01 * q10;
        float n01 = q00 * q01 + q01 * q11;
        float n10 = q10 * q00 + q11 * q10;
        float n11 = q10 * q01 + q11 * q11;
        q00 = n00; q01 = n01; q10 = n10; q11 = n11;
    }
    // vx,vy = inclusive prefix through chunk 2*lane+1
    float px = __shfl_up(vx, 1);
    float py = __shfl_up(vy, 1);
    if (lane == 0) { px = 0.f; py = 0.f; }
    // start state of chunk 2*lane   = prefix through chunk 2*lane-1
    stS[(size_t)(2 * lane) * CHAINS + chain] = make_float2(px, py);
    // start state of chunk 2*lane+1 = S^64 * start0 + e0
    stS[(size_t)(2 * lane + 1) * CHAINS + chain] =
        make_float2(p00 * px + p01 * py + e0.x, p10 * px + p11 * py + e0.y);
}

// ---------------------------------------------------------------------------
// kC: recompute fz -> scan from stS -> x@Cw^T + u@Dw^T -> GELU -> h
//     -> (h@W1^T+b1)*sigmoid(h@W2^T+b2) + u -> out
// ---------------------------------------------------------------------------
__global__ __launch_bounds__(256, 4) void kC(const float* __restrict__ u,
                                             const float* __restrict__ Ad,
                                             const float* __restrict__ Bb,
                                             const float* __restrict__ Cb,
                                             const float* __restrict__ Db,
                                             const float* __restrict__ b1,
                                             const float* __restrict__ b2,
                                             const bf16* __restrict__ wb,
                                             const float2* __restrict__ stS,
                                             float* __restrict__ out) {
    __shared__ bf16 bufU[TS * LDSP];   // u-tile (bf16), lives whole kernel
    __shared__ bf16 bufX[TS * LDSP];   // fz -> x -> h
    const bf16* Bwb = wb;
    const bf16* Cwb = wb + 16384;
    const bf16* Dwb = wb + 32768;
    const bf16* W1b = wb + 49152;
    const bf16* W2b = wb + 65536;

    const int tid  = threadIdx.x;
    const int lane = tid & 63;
    const int wave = tid >> 6;
    const int llo  = lane & 15;
    const int lhi  = lane >> 4;
    const int j0   = wave * 2;
    const size_t rowBase = (size_t)blockIdx.x * TS;

    const int   m   = tid & 127;
    const float a_  = fmaxf(Ad[m], 0.f);
    const float s_  = 1.f / (1.f + a_);
    const float sa_ = s_ * a_;
    const int   b   = blockIdx.x >> 7;
    const int   c   = blockIdx.x & (CHUNKS - 1);
    const float2 st = stS[(size_t)c * CHAINS + b * Mdim + m];
    float bbB[2], bbCD[2], bb1[2], bb2[2];
#pragma unroll
    for (int jj = 0; jj < 2; ++jj) {
        const int col = (j0 + jj) * 16 + llo;
        bbB[jj]  = Bb[col];
        bbCD[jj] = Cb[col] + Db[col];
        bb1[jj]  = b1[col];
        bb2[jj]  = b2[col];
    }

    stage_u(u, rowBase, bufU, tid);
    __syncthreads();

    f32x4 acc[4][2];
#pragma unroll
    for (int rt = 0; rt < 4; ++rt)
#pragma unroll
        for (int jj = 0; jj < 2; ++jj) acc[rt][jj] = (f32x4){0.f, 0.f, 0.f, 0.f};

    // fz = u @ Bw^T + Bb  -> bufX (reads bufU, writes bufX: disjoint, no barrier between)
    pass_colstrip(bufU, Bwb, acc, j0, llo, lhi);
#pragma unroll
    for (int jj = 0; jj < 2; ++jj) {
        const int col = (j0 + jj) * 16 + llo;
#pragma unroll
        for (int rt = 0; rt < 4; ++rt)
#pragma unroll
            for (int r = 0; r < 4; ++r)
                bufX[(rt * 16 + lhi * 4 + r) * LDSP + col] = (bf16)(acc[rt][jj][r] + bbB[jj]);
    }
    __syncthreads();

    // scan from global start state; overwrite bufX with x (= y sequence)
    if (tid < 128) {
        float z = st.x, y = st.y;
#pragma unroll 8
        for (int t = 0; t < TS; ++t) {
            float f  = (float)bufX[t * LDSP + m];
            float zp = z + f;
            float yn = s_ * (zp + y);
            z = s_ * zp - sa_ * y;
            y = yn;
            bufX[t * LDSP + m] = (bf16)y;
        }
    }
    __syncthreads();

    // h = gelu(x@Cw^T + u@Dw^T + Cb + Db)
#pragma unroll
    for (int rt = 0; rt < 4; ++rt)
#pragma unroll
        for (int jj = 0; jj < 2; ++jj) acc[rt][jj] = (f32x4){0.f, 0.f, 0.f, 0.f};
    pass_colstrip(bufX, Cwb, acc, j0, llo, lhi);
    pass_colstrip(bufU, Dwb, acc, j0, llo, lhi);
    __syncthreads();   // other waves' reads of bufX done before overwrite with h
#pragma unroll
    for (int jj = 0; jj < 2; ++jj) {
        const int col = (j0 + jj) * 16 + llo;
#pragma unroll
        for (int rt = 0; rt < 4; ++rt)
#pragma unroll
            for (int r = 0; r < 4; ++r)
                bufX[(rt * 16 + lhi * 4 + r) * LDSP + col] =
                    (bf16)gelu_fast(acc[rt][jj][r] + bbCD[jj]);
    }
    __syncthreads();

    // t2 = h@W2^T + b2 -> sigmoid kept in registers (lane mapping identical to W1 pass)
#pragma unroll
    for (int rt = 0; rt < 4; ++rt)
#pragma unroll
        for (int jj = 0; jj < 2; ++jj) acc[rt][jj] = (f32x4){0.f, 0.f, 0.f, 0.f};
    pass_colstrip(bufX, W2b, acc, j0, llo, lhi);
    f32x4 sig[4][2];
#pragma unroll
    for (int rt = 0; rt < 4; ++rt)
#pragma unroll
        for (int jj = 0; jj < 2; ++jj)
#pragma unroll
            for (int r = 0; r < 4; ++r)
                sig[rt][jj][r] = sigmoid_fast(acc[rt][jj][r] + bb2[jj]);

    // t1 = h@W1^T + b1 (bufX unchanged since last barrier -> no sync needed)
#pragma unroll
    for (int rt = 0; rt < 4; ++rt)
#pragma unroll
        for (int jj = 0; jj < 2; ++jj) acc[rt][jj] = (f32x4){0.f, 0.f, 0.f, 0.f};
    pass_colstrip(bufX, W1b, acc, j0, llo, lhi);

#pragma unroll
    for (int jj = 0; jj < 2; ++jj) {
        const int col = (j0 + jj) * 16 + llo;
#pragma unroll
        for (int rt = 0; rt < 4; ++rt)
#pragma unroll
            for (int r = 0; r < 4; ++r) {
                const int row = rt * 16 + lhi * 4 + r;
                const size_t idx = (rowBase + row) * 128 + col;
                float g = (acc[rt][jj][r] + bb1[jj]) * sig[rt][jj][r];
                out[idx] = g + u[idx];
            }
    }
}

// ---------------------------------------------------------------------------
// launch
// ---------------------------------------------------------------------------
extern "C" void kernel_launch(void* const* d_in, const int* in_sizes, int n_in,
                              void* d_out, int out_size, void* d_ws, size_t ws_size,
                              hipStream_t stream) {
    const float* u  = (const float*)d_in[0];
    const float* Ad = (const float*)d_in[1];
    const float* Bw = (const float*)d_in[2];
    const float* Bb = (const float*)d_in[3];
    const float* Cw = (const float*)d_in[4];
    const float* Cb = (const float*)d_in[5];
    const float* Dw = (const float*)d_in[6];
    const float* Db = (const float*)d_in[7];
    const float* W1 = (const float*)d_in[8];
    const float* b1 = (const float*)d_in[9];
    const float* W2 = (const float*)d_in[10];
    const float* b2 = (const float*)d_in[11];
    float* out = (float*)d_out;

    char* ws = (char*)d_ws;
    bf16*   wb  = (bf16*)ws;                                   // 160 KB
    float2* stE = (float2*)(ws + 256 * 1024);                  // 2 MB  [chain][chunk]
    float2* stS = (float2*)(ws + 256 * 1024 + (size_t)CHUNKS * CHAINS * 8);  // 2 MB [chunk][chain]

    kw_conv<<<5, 256, 0, stream>>>(Bw, Cw, Dw, W1, W2, wb);
    kA<<<NBLK, 256, 0, stream>>>(u, Ad, Bb, wb, stE);
    kB<<<CHAINS / 4, 256, 0, stream>>>(stE, Ad, stS);
    kC<<<NBLK, 256, 0, stream>>>(u, Ad, Bb, Cb, Db, b1, b2, wb, stS, out);
}